// Round 3
// baseline (272.660 us; speedup 1.0000x reference)
//
#include <hip/hip_runtime.h>
#include <math.h>

// Problem constants (fixed by reference setup_inputs)
#define B 8
#define C 256
#define CR 64
#define H 128
#define W 128
#define HW (H*W)              // 16384 = 2^14
#define NELEM (B*C*HW)        // 33554432 = 2^25
#define N4 (NELEM/4)          // 8388608

typedef float floatx4 __attribute__((ext_vector_type(4)));  // clang vector: OK for nontemporal builtins

__device__ __forceinline__ float sigmoidf_(float z) {
    return 1.0f / (1.0f + expf(-z));
}

// ---------------------------------------------------------------------------
// Kernel A: 8 blocks (one per batch), 256 threads. Computes t=(C,), cw=(B,C),
// avg/max over channels, and the full spatial-weight map sw[b,:,:].
// Interior pixels of sw are a per-batch constant (all 49 taps in-bounds);
// only the 3-wide edge band computes real tap sums.
// ---------------------------------------------------------------------------
__global__ __launch_bounds__(256)
void setup_kernel(const float* __restrict__ tf,   // (B,C)
                  const float* __restrict__ pw,   // (C,C) row-major [o][c]
                  const float* __restrict__ pb,   // (C,)
                  const float* __restrict__ g,    // bn_gamma
                  const float* __restrict__ be,   // bn_beta
                  const float* __restrict__ mu,   // bn_mean
                  const float* __restrict__ var,  // bn_var
                  const float* __restrict__ w1,   // (CR,C)
                  const float* __restrict__ b1,   // (CR,)
                  const float* __restrict__ w2,   // (C,CR)
                  const float* __restrict__ b2,   // (C,)
                  const float* __restrict__ saw,  // (1,2,7,7) flat
                  const float* __restrict__ sab,  // (1,)
                  float* __restrict__ cw,         // out (B,C)
                  float* __restrict__ swm)        // out (B,H,W)
{
    const int b   = blockIdx.x;
    const int tid = threadIdx.x;

    __shared__ float tf_sh[C];
    __shared__ float t_sh[C];
    __shared__ float h_sh[CR];
    __shared__ float red[8];
    __shared__ float s_stats[2];   // avg, max

    tf_sh[tid] = tf[b * C + tid];
    __syncthreads();

    // ---- t[c] = relu(BN(proj_w[c,:]·tf[b,:] + pb[c])), thread tid = c ----
    float acc = 0.0f;
    {
        const float4* pwr = reinterpret_cast<const float4*>(pw + tid * C);
        #pragma unroll 8
        for (int k4 = 0; k4 < C / 4; ++k4) {
            const float4 wv = pwr[k4];
            const float* tfk = &tf_sh[k4 * 4];
            acc += wv.x * tfk[0] + wv.y * tfk[1] + wv.z * tfk[2] + wv.w * tfk[3];
        }
    }
    float t;
    {
        const float scale = g[tid] * rsqrtf(var[tid] + 1e-5f);
        t = (acc + pb[tid] - mu[tid]) * scale + be[tid];
        t = fmaxf(t, 0.0f);
        t_sh[tid] = t;
    }

    // ---- per-batch sum / max over C (wave shuffle + LDS combine) ----
    {
        float s = t, m = t;
        #pragma unroll
        for (int off = 32; off > 0; off >>= 1) {
            s += __shfl_down(s, off);
            m  = fmaxf(m, __shfl_down(m, off));
        }
        const int wv_ = tid >> 6;
        if ((tid & 63) == 0) { red[wv_] = s; red[4 + wv_] = m; }
        __syncthreads();
        if (tid == 0) {
            s_stats[0] = (red[0] + red[1] + red[2] + red[3]) * (1.0f / C);
            s_stats[1] = fmaxf(fmaxf(red[4], red[5]), fmaxf(red[6], red[7]));
        }
        __syncthreads();
    }

    // ---- h[r] = relu(ca_w1[r,:]·t + b1[r]), threads 0..63 ----
    if (tid < CR) {
        float a = b1[tid];
        const float4* w1r = reinterpret_cast<const float4*>(w1 + tid * C);
        #pragma unroll 8
        for (int k4 = 0; k4 < C / 4; ++k4) {
            const float4 wv = w1r[k4];
            const float* tk = &t_sh[k4 * 4];
            a += wv.x * tk[0] + wv.y * tk[1] + wv.z * tk[2] + wv.w * tk[3];
        }
        h_sh[tid] = fmaxf(a, 0.0f);
    }
    __syncthreads();

    // ---- cw[c] = sigmoid(ca_w2[c,:]·h + b2[c]) ----
    {
        float a = b2[tid];
        const float4* w2r = reinterpret_cast<const float4*>(w2 + tid * CR);
        #pragma unroll
        for (int r4 = 0; r4 < CR / 4; ++r4) {
            const float4 wv = w2r[r4];
            const float* hk = &h_sh[r4 * 4];
            a += wv.x * hk[0] + wv.y * hk[1] + wv.z * hk[2] + wv.w * hk[3];
        }
        cw[b * C + tid] = sigmoidf_(a);
    }

    // ---- sw map for this batch ----
    {
        const float avgv = s_stats[0];
        const float maxv = s_stats[1];
        const float bias = sab[0];
        float T0 = 0.0f, T1 = 0.0f;
        #pragma unroll
        for (int i = 0; i < 49; ++i) { T0 += saw[i]; T1 += saw[49 + i]; }
        const float interior = sigmoidf_(avgv * T0 + maxv * T1 + bias);

        for (int s_ = tid; s_ < HW; s_ += 256) {
            const int y = s_ >> 7;
            const int x = s_ & (W - 1);
            float v;
            if (y >= 3 && y <= H - 4 && x >= 3 && x <= W - 4) {
                v = interior;
            } else {
                const int ky0 = max(0, 3 - y), ky1 = min(6, H + 2 - y);
                const int kx0 = max(0, 3 - x), kx1 = min(6, W + 2 - x);
                float S0 = 0.0f, S1 = 0.0f;
                for (int ky = ky0; ky <= ky1; ++ky)
                    for (int kx = kx0; kx <= kx1; ++kx) {
                        S0 += saw[ky * 7 + kx];
                        S1 += saw[49 + ky * 7 + kx];
                    }
                v = sigmoidf_(avgv * S0 + maxv * S1 + bias);
            }
            swm[b * HW + s_] = v;
        }
    }
}

// ---------------------------------------------------------------------------
// Kernel C: out = x * cw[b,c] * sw[b,y,x], float4 grid-stride. Memory-bound.
// x/out are streamed (nontemporal); cw/sw are tiny and cache-resident.
// ---------------------------------------------------------------------------
__global__ __launch_bounds__(256)
void fuse_kernel(const floatx4* __restrict__ x4,
                 const float*   __restrict__ cw,    // (B,C)
                 const float4*  __restrict__ sw4,   // (B,HW/4)
                 floatx4* __restrict__ out4)
{
    const int stride = gridDim.x * blockDim.x;
    for (int j = blockIdx.x * blockDim.x + threadIdx.x; j < N4; j += stride) {
        const int s4 = j & 4095;          // HW/4 = 4096
        const int c  = (j >> 12) & 255;
        const int b  = j >> 20;           // C*HW/4 = 2^20
        const float cwv = cw[(b << 8) + c];
        const floatx4 xs = __builtin_nontemporal_load(&x4[j]);
        const float4 sws = sw4[(b << 12) + s4];
        floatx4 o;
        o.x = xs.x * cwv * sws.x;
        o.y = xs.y * cwv * sws.y;
        o.z = xs.z * cwv * sws.z;
        o.w = xs.w * cwv * sws.w;
        __builtin_nontemporal_store(o, &out4[j]);
    }
}

// ---------------------------------------------------------------------------
extern "C" void kernel_launch(void* const* d_in, const int* in_sizes, int n_in,
                              void* d_out, int out_size, void* d_ws, size_t ws_size,
                              hipStream_t stream) {
    const float* x    = (const float*)d_in[0];
    const float* tf   = (const float*)d_in[1];
    const float* pw   = (const float*)d_in[2];
    const float* pb   = (const float*)d_in[3];
    const float* g    = (const float*)d_in[4];
    const float* be   = (const float*)d_in[5];
    const float* mu   = (const float*)d_in[6];
    const float* var  = (const float*)d_in[7];
    const float* w1   = (const float*)d_in[8];
    const float* b1   = (const float*)d_in[9];
    const float* w2   = (const float*)d_in[10];
    const float* b2   = (const float*)d_in[11];
    const float* saw  = (const float*)d_in[12];
    const float* sab  = (const float*)d_in[13];
    float* out = (float*)d_out;

    // workspace layout (floats): cw[2048] | sw[131072]
    float* wsf   = (float*)d_ws;
    float* cw    = wsf;
    float* swm   = wsf + 2048;   // byte offset 8192, 16B-aligned

    setup_kernel<<<B, 256, 0, stream>>>(tf, pw, pb, g, be, mu, var,
                                        w1, b1, w2, b2, saw, sab, cw, swm);
    fuse_kernel<<<2048, 256, 0, stream>>>((const float*)x ? (const floatx4*)x : nullptr, cw,
                                          (const float4*)swm, (floatx4*)out);
}

// Round 4
// 69.940 us; speedup vs baseline: 3.8985x; 3.8985x over previous
//
#include <hip/hip_runtime.h>
#include <math.h>

// Problem constants (fixed by reference setup_inputs)
#define B 8
#define C 256
#define CR 64
#define H 128
#define W 128
#define HW (H*W)              // 16384 = 2^14
#define NELEM (B*C*HW)        // 33554432 = 2^25
#define N4 (NELEM/4)          // 8388608

typedef float floatx4 __attribute__((ext_vector_type(4)));  // clang vector: OK for nontemporal builtins

__device__ __forceinline__ float sigmoidf_(float z) {
    return 1.0f / (1.0f + expf(-z));
}

// ---------------------------------------------------------------------------
// Kernel A: 8 blocks (one per batch), 256 threads. Computes t=(C,), cw=(B,C),
// avg/max over channels, and the full spatial-weight map sw[b,:,:].
// sw takes only 49 distinct values per batch (7 y-classes x 7 x-classes of
// in-bounds 7x7 tap ranges), so we build a 49-entry sigmoid table in LDS and
// the HW-pixel store loop is a pure LDS lookup + coalesced store.
// ---------------------------------------------------------------------------
__global__ __launch_bounds__(256)
void setup_kernel(const float* __restrict__ tf,   // (B,C)
                  const float* __restrict__ pw,   // (C,C) row-major [o][c]
                  const float* __restrict__ pb,   // (C,)
                  const float* __restrict__ g,    // bn_gamma
                  const float* __restrict__ be,   // bn_beta
                  const float* __restrict__ mu,   // bn_mean
                  const float* __restrict__ var,  // bn_var
                  const float* __restrict__ w1,   // (CR,C)
                  const float* __restrict__ b1,   // (CR,)
                  const float* __restrict__ w2,   // (C,CR)
                  const float* __restrict__ b2,   // (C,)
                  const float* __restrict__ saw,  // (1,2,7,7) flat
                  const float* __restrict__ sab,  // (1,)
                  float* __restrict__ cw,         // out (B,C)
                  float* __restrict__ swm)        // out (B,H,W)
{
    const int b   = blockIdx.x;
    const int tid = threadIdx.x;

    __shared__ float tf_sh[C];
    __shared__ float t_sh[C];
    __shared__ float h_sh[CR];
    __shared__ float red[8];
    __shared__ float s_stats[2];   // avg, max
    __shared__ float saw_sh[98];
    __shared__ float table[49];    // sw values by (yclass*7 + xclass)

    tf_sh[tid] = tf[b * C + tid];
    if (tid < 98) saw_sh[tid] = saw[tid];
    __syncthreads();

    // ---- t[c] = relu(BN(proj_w[c,:]·tf[b,:] + pb[c])), thread tid = c ----
    float acc = 0.0f;
    {
        const float4* pwr = reinterpret_cast<const float4*>(pw + tid * C);
        #pragma unroll 8
        for (int k4 = 0; k4 < C / 4; ++k4) {
            const float4 wv = pwr[k4];
            const float* tfk = &tf_sh[k4 * 4];
            acc += wv.x * tfk[0] + wv.y * tfk[1] + wv.z * tfk[2] + wv.w * tfk[3];
        }
    }
    float t;
    {
        const float scale = g[tid] * rsqrtf(var[tid] + 1e-5f);
        t = (acc + pb[tid] - mu[tid]) * scale + be[tid];
        t = fmaxf(t, 0.0f);
        t_sh[tid] = t;
    }

    // ---- per-batch sum / max over C (wave shuffle + LDS combine) ----
    {
        float s = t, m = t;
        #pragma unroll
        for (int off = 32; off > 0; off >>= 1) {
            s += __shfl_down(s, off);
            m  = fmaxf(m, __shfl_down(m, off));
        }
        const int wv_ = tid >> 6;
        if ((tid & 63) == 0) { red[wv_] = s; red[4 + wv_] = m; }
        __syncthreads();
        if (tid == 0) {
            s_stats[0] = (red[0] + red[1] + red[2] + red[3]) * (1.0f / C);
            s_stats[1] = fmaxf(fmaxf(red[4], red[5]), fmaxf(red[6], red[7]));
        }
        __syncthreads();
    }

    // ---- 49-entry sw table: threads 0..48, all taps from LDS ----
    if (tid < 49) {
        const int yc = tid / 7, xc = tid % 7;
        const int ky0 = yc < 3 ? 3 - yc : 0;
        const int ky1 = yc > 3 ? 9 - yc : 6;   // yc=4->5, 5->4, 6->3
        const int kx0 = xc < 3 ? 3 - xc : 0;
        const int kx1 = xc > 3 ? 9 - xc : 6;
        float S0 = 0.0f, S1 = 0.0f;
        for (int ky = ky0; ky <= ky1; ++ky)
            for (int kx = kx0; kx <= kx1; ++kx) {
                S0 += saw_sh[ky * 7 + kx];
                S1 += saw_sh[49 + ky * 7 + kx];
            }
        table[tid] = sigmoidf_(s_stats[0] * S0 + s_stats[1] * S1 + sab[0]);
    }

    // ---- h[r] = relu(ca_w1[r,:]·t + b1[r]), threads 0..63 ----
    if (tid < CR) {
        float a = b1[tid];
        const float4* w1r = reinterpret_cast<const float4*>(w1 + tid * C);
        #pragma unroll 8
        for (int k4 = 0; k4 < C / 4; ++k4) {
            const float4 wv = w1r[k4];
            const float* tk = &t_sh[k4 * 4];
            a += wv.x * tk[0] + wv.y * tk[1] + wv.z * tk[2] + wv.w * tk[3];
        }
        h_sh[tid] = fmaxf(a, 0.0f);
    }
    __syncthreads();

    // ---- cw[c] = sigmoid(ca_w2[c,:]·h + b2[c]) ----
    {
        float a = b2[tid];
        const float4* w2r = reinterpret_cast<const float4*>(w2 + tid * CR);
        #pragma unroll
        for (int r4 = 0; r4 < CR / 4; ++r4) {
            const float4 wv = w2r[r4];
            const float* hk = &h_sh[r4 * 4];
            a += wv.x * hk[0] + wv.y * hk[1] + wv.z * hk[2] + wv.w * hk[3];
        }
        cw[b * C + tid] = sigmoidf_(a);
    }

    // ---- sw map for this batch: pure LDS lookup + coalesced store ----
    for (int s_ = tid; s_ < HW; s_ += 256) {
        const int y = s_ >> 7;
        const int x = s_ & (W - 1);
        const int yc = y < 3 ? y : (y > 124 ? y - 121 : 3);
        const int xc = x < 3 ? x : (x > 124 ? x - 121 : 3);
        swm[b * HW + s_] = table[yc * 7 + xc];
    }
}

// ---------------------------------------------------------------------------
// Kernel C: out = x * cw[b,c] * sw[b,y,x], float4 grid-stride. Memory-bound.
// x/out are streamed (nontemporal); cw/sw are tiny and cache-resident.
// ---------------------------------------------------------------------------
__global__ __launch_bounds__(256)
void fuse_kernel(const floatx4* __restrict__ x4,
                 const float*   __restrict__ cw,    // (B,C)
                 const float4*  __restrict__ sw4,   // (B,HW/4)
                 floatx4* __restrict__ out4)
{
    const int stride = gridDim.x * blockDim.x;
    for (int j = blockIdx.x * blockDim.x + threadIdx.x; j < N4; j += stride) {
        const int s4 = j & 4095;          // HW/4 = 4096
        const int c  = (j >> 12) & 255;
        const int b  = j >> 20;           // C*HW/4 = 2^20
        const float cwv = cw[(b << 8) + c];
        const floatx4 xs = __builtin_nontemporal_load(&x4[j]);
        const float4 sws = sw4[(b << 12) + s4];
        floatx4 o;
        o.x = xs.x * cwv * sws.x;
        o.y = xs.y * cwv * sws.y;
        o.z = xs.z * cwv * sws.z;
        o.w = xs.w * cwv * sws.w;
        __builtin_nontemporal_store(o, &out4[j]);
    }
}

// ---------------------------------------------------------------------------
extern "C" void kernel_launch(void* const* d_in, const int* in_sizes, int n_in,
                              void* d_out, int out_size, void* d_ws, size_t ws_size,
                              hipStream_t stream) {
    const float* x    = (const float*)d_in[0];
    const float* tf   = (const float*)d_in[1];
    const float* pw   = (const float*)d_in[2];
    const float* pb   = (const float*)d_in[3];
    const float* g    = (const float*)d_in[4];
    const float* be   = (const float*)d_in[5];
    const float* mu   = (const float*)d_in[6];
    const float* var  = (const float*)d_in[7];
    const float* w1   = (const float*)d_in[8];
    const float* b1   = (const float*)d_in[9];
    const float* w2   = (const float*)d_in[10];
    const float* b2   = (const float*)d_in[11];
    const float* saw  = (const float*)d_in[12];
    const float* sab  = (const float*)d_in[13];
    float* out = (float*)d_out;

    // workspace layout (floats): cw[2048] | sw[131072]
    float* wsf   = (float*)d_ws;
    float* cw    = wsf;
    float* swm   = wsf + 2048;   // byte offset 8192, 16B-aligned

    setup_kernel<<<B, 256, 0, stream>>>(tf, pw, pb, g, be, mu, var,
                                        w1, b1, w2, b2, saw, sab, cw, swm);
    fuse_kernel<<<2048, 256, 0, stream>>>((const floatx4*)x, cw,
                                          (const float4*)swm, (floatx4*)out);
}

// Round 5
// 69.081 us; speedup vs baseline: 3.9470x; 1.0124x over previous
//
#include <hip/hip_runtime.h>
#include <math.h>

// Problem constants (fixed by reference setup_inputs)
#define B 8
#define C 256
#define CR 64
#define H 128
#define W 128
#define HW (H*W)              // 16384 = 2^14
#define NELEM (B*C*HW)        // 33554432 = 2^25
#define N4 (NELEM/4)          // 8388608

typedef float floatx4 __attribute__((ext_vector_type(4)));  // clang vector for nontemporal builtins

__device__ __forceinline__ float sigmoidf_(float z) {
    return 1.0f / (1.0f + expf(-z));
}

// ---------------------------------------------------------------------------
// Kernel A: 8 blocks (one per batch), 256 threads. Computes cw=(B,C) and the
// 49-entry sw class table per batch (7 y-classes x 7 x-classes of in-bounds
// 7x7 tap sums). No spatial map is materialized.
// ---------------------------------------------------------------------------
__global__ __launch_bounds__(256)
void setup_kernel(const float* __restrict__ tf,   // (B,C)
                  const float* __restrict__ pw,   // (C,C) row-major [o][c]
                  const float* __restrict__ pb,   // (C,)
                  const float* __restrict__ g,    // bn_gamma
                  const float* __restrict__ be,   // bn_beta
                  const float* __restrict__ mu,   // bn_mean
                  const float* __restrict__ var,  // bn_var
                  const float* __restrict__ w1,   // (CR,C)
                  const float* __restrict__ b1,   // (CR,)
                  const float* __restrict__ w2,   // (C,CR)
                  const float* __restrict__ b2,   // (C,)
                  const float* __restrict__ saw,  // (1,2,7,7) flat
                  const float* __restrict__ sab,  // (1,)
                  float* __restrict__ cw,         // out (B,C)
                  float* __restrict__ tbl)        // out (B,49)
{
    const int b   = blockIdx.x;
    const int tid = threadIdx.x;

    __shared__ float tf_sh[C];
    __shared__ float t_sh[C];
    __shared__ float h_sh[CR];
    __shared__ float red[8];
    __shared__ float s_stats[2];   // avg, max
    __shared__ float saw_sh[98];

    tf_sh[tid] = tf[b * C + tid];
    if (tid < 98) saw_sh[tid] = saw[tid];
    __syncthreads();

    // ---- t[c] = relu(BN(proj_w[c,:]·tf[b,:] + pb[c])), thread tid = c ----
    float acc = 0.0f;
    {
        const float4* pwr = reinterpret_cast<const float4*>(pw + tid * C);
        #pragma unroll 16
        for (int k4 = 0; k4 < C / 4; ++k4) {
            const float4 wv = pwr[k4];
            const float* tfk = &tf_sh[k4 * 4];
            acc += wv.x * tfk[0] + wv.y * tfk[1] + wv.z * tfk[2] + wv.w * tfk[3];
        }
    }
    float t;
    {
        const float scale = g[tid] * rsqrtf(var[tid] + 1e-5f);
        t = (acc + pb[tid] - mu[tid]) * scale + be[tid];
        t = fmaxf(t, 0.0f);
        t_sh[tid] = t;
    }

    // ---- per-batch sum / max over C (wave shuffle + LDS combine) ----
    {
        float s = t, m = t;
        #pragma unroll
        for (int off = 32; off > 0; off >>= 1) {
            s += __shfl_down(s, off);
            m  = fmaxf(m, __shfl_down(m, off));
        }
        const int wv_ = tid >> 6;
        if ((tid & 63) == 0) { red[wv_] = s; red[4 + wv_] = m; }
        __syncthreads();
        if (tid == 0) {
            s_stats[0] = (red[0] + red[1] + red[2] + red[3]) * (1.0f / C);
            s_stats[1] = fmaxf(fmaxf(red[4], red[5]), fmaxf(red[6], red[7]));
        }
        __syncthreads();
    }

    // ---- 49-entry sw table: threads 0..48, taps from LDS ----
    if (tid < 49) {
        const int yc = tid / 7, xc = tid % 7;
        const int ky0 = yc < 3 ? 3 - yc : 0;
        const int ky1 = yc > 3 ? 9 - yc : 6;   // yc=4->5, 5->4, 6->3
        const int kx0 = xc < 3 ? 3 - xc : 0;
        const int kx1 = xc > 3 ? 9 - xc : 6;
        float S0 = 0.0f, S1 = 0.0f;
        for (int ky = ky0; ky <= ky1; ++ky)
            for (int kx = kx0; kx <= kx1; ++kx) {
                S0 += saw_sh[ky * 7 + kx];
                S1 += saw_sh[49 + ky * 7 + kx];
            }
        tbl[b * 49 + tid] = sigmoidf_(s_stats[0] * S0 + s_stats[1] * S1 + sab[0]);
    }

    // ---- h[r] = relu(ca_w1[r,:]·t + b1[r]), threads 0..63 ----
    if (tid < CR) {
        float a = b1[tid];
        const float4* w1r = reinterpret_cast<const float4*>(w1 + tid * C);
        #pragma unroll 16
        for (int k4 = 0; k4 < C / 4; ++k4) {
            const float4 wv = w1r[k4];
            const float* tk = &t_sh[k4 * 4];
            a += wv.x * tk[0] + wv.y * tk[1] + wv.z * tk[2] + wv.w * tk[3];
        }
        h_sh[tid] = fmaxf(a, 0.0f);
    }
    __syncthreads();

    // ---- cw[c] = sigmoid(ca_w2[c,:]·h + b2[c]) ----
    {
        float a = b2[tid];
        const float4* w2r = reinterpret_cast<const float4*>(w2 + tid * CR);
        #pragma unroll
        for (int r4 = 0; r4 < CR / 4; ++r4) {
            const float4 wv = w2r[r4];
            const float* hk = &h_sh[r4 * 4];
            a += wv.x * hk[0] + wv.y * hk[1] + wv.z * hk[2] + wv.w * hk[3];
        }
        cw[b * C + tid] = sigmoidf_(a);
    }
}

// ---------------------------------------------------------------------------
// Kernel C: out[b,c,y,x] = x * cw[b,c] * sw_table[b][yc(y)][xc(x)].
// cw (8KB) + tables (1.5KB) live in LDS; inner loop is a pure float4 stream.
// ---------------------------------------------------------------------------
__global__ __launch_bounds__(256)
void fuse_kernel(const floatx4* __restrict__ x4,
                 const float*   __restrict__ cw,    // (B,C)
                 const float*   __restrict__ tbl,   // (B,49)
                 floatx4* __restrict__ out4)
{
    __shared__ float cw_sh[B * C];     // 2048 floats
    __shared__ float tbl_sh[B * 49];   // 392 floats

    const int tid = threadIdx.x;
    {
        const float4* cwsrc = reinterpret_cast<const float4*>(cw);
        float4* cwdst = reinterpret_cast<float4*>(cw_sh);
        #pragma unroll
        for (int i = tid; i < (B * C) / 4; i += 256) cwdst[i] = cwsrc[i];
        for (int i = tid; i < B * 49; i += 256) tbl_sh[i] = tbl[i];
    }
    __syncthreads();

    const int stride = gridDim.x * blockDim.x;
    for (int j = blockIdx.x * blockDim.x + tid; j < N4; j += stride) {
        const int s4 = j & 4095;          // HW/4 = 4096 float4 per plane
        const int bc = j >> 12;           // b*256 + c
        const int b  = bc >> 8;
        const int y  = s4 >> 5;           // 32 float4 per row
        const int xg = s4 & 31;
        const int yc = y < 3 ? y : (y > 124 ? y - 121 : 3);

        const float cwv = cw_sh[bc];
        const float* tb = &tbl_sh[b * 49 + yc * 7];
        float s0, s1, s2, s3;
        if (xg == 0)       { s0 = tb[0]; s1 = tb[1]; s2 = tb[2]; s3 = tb[3]; }
        else if (xg == 31) { s0 = tb[3]; s1 = tb[4]; s2 = tb[5]; s3 = tb[6]; }
        else               { s0 = s1 = s2 = s3 = tb[3]; }

        const floatx4 xs = __builtin_nontemporal_load(&x4[j]);
        floatx4 o;
        o.x = xs.x * cwv * s0;
        o.y = xs.y * cwv * s1;
        o.z = xs.z * cwv * s2;
        o.w = xs.w * cwv * s3;
        __builtin_nontemporal_store(o, &out4[j]);
    }
}

// ---------------------------------------------------------------------------
extern "C" void kernel_launch(void* const* d_in, const int* in_sizes, int n_in,
                              void* d_out, int out_size, void* d_ws, size_t ws_size,
                              hipStream_t stream) {
    const float* x    = (const float*)d_in[0];
    const float* tf   = (const float*)d_in[1];
    const float* pw   = (const float*)d_in[2];
    const float* pb   = (const float*)d_in[3];
    const float* g    = (const float*)d_in[4];
    const float* be   = (const float*)d_in[5];
    const float* mu   = (const float*)d_in[6];
    const float* var  = (const float*)d_in[7];
    const float* w1   = (const float*)d_in[8];
    const float* b1   = (const float*)d_in[9];
    const float* w2   = (const float*)d_in[10];
    const float* b2   = (const float*)d_in[11];
    const float* saw  = (const float*)d_in[12];
    const float* sab  = (const float*)d_in[13];
    float* out = (float*)d_out;

    // workspace layout (floats): cw[2048] | tbl[392]
    float* wsf = (float*)d_ws;
    float* cw  = wsf;
    float* tbl = wsf + 2048;

    setup_kernel<<<B, 256, 0, stream>>>(tf, pw, pb, g, be, mu, var,
                                        w1, b1, w2, b2, saw, sab, cw, tbl);
    fuse_kernel<<<2048, 256, 0, stream>>>((const floatx4*)x, cw, tbl,
                                          (floatx4*)out);
}

// Round 6
// 67.612 us; speedup vs baseline: 4.0327x; 1.0217x over previous
//
#include <hip/hip_runtime.h>
#include <math.h>

// Problem constants (fixed by reference setup_inputs)
#define B 8
#define C 256
#define CR 64
#define H 128
#define W 128
#define HW (H*W)              // 16384 = 2^14
#define NELEM (B*C*HW)        // 33554432 = 2^25
#define N4 (NELEM/4)          // 8388608
#define PER_BATCH4 (C*HW/4)   // 1048576 = 2^20 float4 per batch
#define FUSE_BLOCKS_X 1024
#define FUSE_ITERS 4
#define FUSE_STRIDE (FUSE_BLOCKS_X*256)   // 262144, multiple of 4096

typedef float floatx4 __attribute__((ext_vector_type(4)));  // clang vector for nontemporal builtins

__device__ __forceinline__ float sigmoidf_(float z) {
    return 1.0f / (1.0f + expf(-z));
}

// ---------------------------------------------------------------------------
// Kernel A: 8 blocks (one per batch), 256 threads. Computes cw=(B,C) and the
// 49-entry sw class table per batch (7 y-classes x 7 x-classes of in-bounds
// 7x7 tap sums). No spatial map is materialized.
// ---------------------------------------------------------------------------
__global__ __launch_bounds__(256)
void setup_kernel(const float* __restrict__ tf,   // (B,C)
                  const float* __restrict__ pw,   // (C,C) row-major [o][c]
                  const float* __restrict__ pb,   // (C,)
                  const float* __restrict__ g,    // bn_gamma
                  const float* __restrict__ be,   // bn_beta
                  const float* __restrict__ mu,   // bn_mean
                  const float* __restrict__ var,  // bn_var
                  const float* __restrict__ w1,   // (CR,C)
                  const float* __restrict__ b1,   // (CR,)
                  const float* __restrict__ w2,   // (C,CR)
                  const float* __restrict__ b2,   // (C,)
                  const float* __restrict__ saw,  // (1,2,7,7) flat
                  const float* __restrict__ sab,  // (1,)
                  float* __restrict__ cw,         // out (B,C)
                  float* __restrict__ tbl)        // out (B,49)
{
    const int b   = blockIdx.x;
    const int tid = threadIdx.x;

    __shared__ float tf_sh[C];
    __shared__ float t_sh[C];
    __shared__ float h_sh[CR];
    __shared__ float red[8];
    __shared__ float s_stats[2];   // avg, max
    __shared__ float saw_sh[98];

    tf_sh[tid] = tf[b * C + tid];
    if (tid < 98) saw_sh[tid] = saw[tid];
    __syncthreads();

    // ---- t[c] = relu(BN(proj_w[c,:]·tf[b,:] + pb[c])), thread tid = c ----
    float acc = 0.0f;
    {
        const float4* pwr = reinterpret_cast<const float4*>(pw + tid * C);
        #pragma unroll 16
        for (int k4 = 0; k4 < C / 4; ++k4) {
            const float4 wv = pwr[k4];
            const float* tfk = &tf_sh[k4 * 4];
            acc += wv.x * tfk[0] + wv.y * tfk[1] + wv.z * tfk[2] + wv.w * tfk[3];
        }
    }
    float t;
    {
        const float scale = g[tid] * rsqrtf(var[tid] + 1e-5f);
        t = (acc + pb[tid] - mu[tid]) * scale + be[tid];
        t = fmaxf(t, 0.0f);
        t_sh[tid] = t;
    }

    // ---- per-batch sum / max over C (wave shuffle + LDS combine) ----
    {
        float s = t, m = t;
        #pragma unroll
        for (int off = 32; off > 0; off >>= 1) {
            s += __shfl_down(s, off);
            m  = fmaxf(m, __shfl_down(m, off));
        }
        const int wv_ = tid >> 6;
        if ((tid & 63) == 0) { red[wv_] = s; red[4 + wv_] = m; }
        __syncthreads();
        if (tid == 0) {
            s_stats[0] = (red[0] + red[1] + red[2] + red[3]) * (1.0f / C);
            s_stats[1] = fmaxf(fmaxf(red[4], red[5]), fmaxf(red[6], red[7]));
        }
        __syncthreads();
    }

    // ---- 49-entry sw table: threads 0..48, taps from LDS ----
    if (tid < 49) {
        const int yc = tid / 7, xc = tid % 7;
        const int ky0 = yc < 3 ? 3 - yc : 0;
        const int ky1 = yc > 3 ? 9 - yc : 6;   // yc=4->5, 5->4, 6->3
        const int kx0 = xc < 3 ? 3 - xc : 0;
        const int kx1 = xc > 3 ? 9 - xc : 6;
        float S0 = 0.0f, S1 = 0.0f;
        for (int ky = ky0; ky <= ky1; ++ky)
            for (int kx = kx0; kx <= kx1; ++kx) {
                S0 += saw_sh[ky * 7 + kx];
                S1 += saw_sh[49 + ky * 7 + kx];
            }
        tbl[b * 49 + tid] = sigmoidf_(s_stats[0] * S0 + s_stats[1] * S1 + sab[0]);
    }

    // ---- h[r] = relu(ca_w1[r,:]·t + b1[r]), threads 0..63 ----
    if (tid < CR) {
        float a = b1[tid];
        const float4* w1r = reinterpret_cast<const float4*>(w1 + tid * C);
        #pragma unroll 16
        for (int k4 = 0; k4 < C / 4; ++k4) {
            const float4 wv = w1r[k4];
            const float* tk = &t_sh[k4 * 4];
            a += wv.x * tk[0] + wv.y * tk[1] + wv.z * tk[2] + wv.w * tk[3];
        }
        h_sh[tid] = fmaxf(a, 0.0f);
    }
    __syncthreads();

    // ---- cw[c] = sigmoid(ca_w2[c,:]·h + b2[c]) ----
    {
        float a = b2[tid];
        const float4* w2r = reinterpret_cast<const float4*>(w2 + tid * CR);
        #pragma unroll
        for (int r4 = 0; r4 < CR / 4; ++r4) {
            const float4 wv = w2r[r4];
            const float* hk = &h_sh[r4 * 4];
            a += wv.x * hk[0] + wv.y * hk[1] + wv.z * hk[2] + wv.w * hk[3];
        }
        cw[b * C + tid] = sigmoidf_(a);
    }
}

// ---------------------------------------------------------------------------
// Kernel C: out[b,c,y,x] = x * cw[b,c] * sw_class_value.
// Grid (1024, B): b constant per block; per-thread spatial class constant
// across all iterations (stride 262144 is a multiple of 4096), so ALL spatial
// work hoists out of the loop. Inner loop: x-load, LDS-broadcast cw, 8 fmul,
// store.
// ---------------------------------------------------------------------------
__global__ __launch_bounds__(256)
void fuse_kernel(const floatx4* __restrict__ x4,
                 const float*   __restrict__ cw,    // (B,C)
                 const float*   __restrict__ tbl,   // (B,49)
                 floatx4* __restrict__ out4)
{
    __shared__ float cw_sh[C];      // this batch's channel weights
    __shared__ float tbl_sh[49];    // this batch's sw class table

    const int b   = blockIdx.y;
    const int tid = threadIdx.x;
    cw_sh[tid] = cw[b * C + tid];
    if (tid < 49) tbl_sh[tid] = tbl[b * 49 + tid];
    __syncthreads();

    const int local0 = blockIdx.x * 256 + tid;     // [0, 262144)
    // spatial classification — constant across iterations
    const int s4 = local0 & 4095;                  // float4 index within plane
    const int y  = s4 >> 5;                        // 32 float4 per row
    const int xg = s4 & 31;
    const int yc = y < 3 ? y : (y > 124 ? y - 121 : 3);
    const float* tb = &tbl_sh[yc * 7];
    float s0, s1, s2, s3;
    if (xg == 0)       { s0 = tb[0]; s1 = tb[1]; s2 = tb[2]; s3 = tb[3]; }
    else if (xg == 31) { s0 = tb[3]; s1 = tb[4]; s2 = tb[5]; s3 = tb[6]; }
    else               { s0 = s1 = s2 = s3 = tb[3]; }

    const long base = (long)b * PER_BATCH4;
    const int  c0   = local0 >> 12;                // channel of iter 0

    #pragma unroll
    for (int i = 0; i < FUSE_ITERS; ++i) {
        const long j   = base + local0 + (long)i * FUSE_STRIDE;
        const float cwv = cw_sh[c0 + i * (FUSE_STRIDE >> 12)];
        const floatx4 xs = __builtin_nontemporal_load(&x4[j]);
        floatx4 o;
        o.x = xs.x * cwv * s0;
        o.y = xs.y * cwv * s1;
        o.z = xs.z * cwv * s2;
        o.w = xs.w * cwv * s3;
        __builtin_nontemporal_store(o, &out4[j]);
    }
}

// ---------------------------------------------------------------------------
extern "C" void kernel_launch(void* const* d_in, const int* in_sizes, int n_in,
                              void* d_out, int out_size, void* d_ws, size_t ws_size,
                              hipStream_t stream) {
    const float* x    = (const float*)d_in[0];
    const float* tf   = (const float*)d_in[1];
    const float* pw   = (const float*)d_in[2];
    const float* pb   = (const float*)d_in[3];
    const float* g    = (const float*)d_in[4];
    const float* be   = (const float*)d_in[5];
    const float* mu   = (const float*)d_in[6];
    const float* var  = (const float*)d_in[7];
    const float* w1   = (const float*)d_in[8];
    const float* b1   = (const float*)d_in[9];
    const float* w2   = (const float*)d_in[10];
    const float* b2   = (const float*)d_in[11];
    const float* saw  = (const float*)d_in[12];
    const float* sab  = (const float*)d_in[13];
    float* out = (float*)d_out;

    // workspace layout (floats): cw[2048] | tbl[392]
    float* wsf = (float*)d_ws;
    float* cw  = wsf;
    float* tbl = wsf + 2048;

    setup_kernel<<<B, 256, 0, stream>>>(tf, pw, pb, g, be, mu, var,
                                        w1, b1, w2, b2, saw, sab, cw, tbl);
    fuse_kernel<<<dim3(FUSE_BLOCKS_X, B), 256, 0, stream>>>(
        (const floatx4*)x, cw, tbl, (floatx4*)out);
}

// Round 7
// 67.282 us; speedup vs baseline: 4.0525x; 1.0049x over previous
//
#include <hip/hip_runtime.h>
#include <math.h>

// Problem constants (fixed by reference setup_inputs)
#define B 8
#define C 256
#define CR 64
#define H 128
#define W 128
#define HW (H*W)              // 16384 = 2^14
#define NELEM (B*C*HW)        // 33554432 = 2^25
#define N4 (NELEM/4)          // 8388608
#define PER_BATCH4 (C*HW/4)   // 1048576 = 2^20 float4 per batch
#define FUSE_BLOCKS_X 1024
#define FUSE_ITERS 4
#define FUSE_STRIDE (FUSE_BLOCKS_X*256)   // 262144, multiple of 4096

typedef float floatx4 __attribute__((ext_vector_type(4)));

__device__ __forceinline__ float sigmoidf_(float z) {
    return 1.0f / (1.0f + expf(-z));
}

// ---------------------------------------------------------------------------
// Kernel A: 8 blocks (one per batch), 256 threads. Computes cw=(B,C) and the
// 49-entry sw class table per batch (7 y-classes x 7 x-classes of in-bounds
// 7x7 tap sums). No spatial map is materialized.
// ---------------------------------------------------------------------------
__global__ __launch_bounds__(256)
void setup_kernel(const float* __restrict__ tf,   // (B,C)
                  const float* __restrict__ pw,   // (C,C) row-major [o][c]
                  const float* __restrict__ pb,   // (C,)
                  const float* __restrict__ g,    // bn_gamma
                  const float* __restrict__ be,   // bn_beta
                  const float* __restrict__ mu,   // bn_mean
                  const float* __restrict__ var,  // bn_var
                  const float* __restrict__ w1,   // (CR,C)
                  const float* __restrict__ b1,   // (CR,)
                  const float* __restrict__ w2,   // (C,CR)
                  const float* __restrict__ b2,   // (C,)
                  const float* __restrict__ saw,  // (1,2,7,7) flat
                  const float* __restrict__ sab,  // (1,)
                  float* __restrict__ cw,         // out (B,C)
                  float* __restrict__ tbl)        // out (B,49)
{
    const int b   = blockIdx.x;
    const int tid = threadIdx.x;

    __shared__ float tf_sh[C];
    __shared__ float t_sh[C];
    __shared__ float h_sh[CR];
    __shared__ float red[8];
    __shared__ float s_stats[2];   // avg, max
    __shared__ float saw_sh[98];

    tf_sh[tid] = tf[b * C + tid];
    if (tid < 98) saw_sh[tid] = saw[tid];
    __syncthreads();

    // ---- t[c] = relu(BN(proj_w[c,:]·tf[b,:] + pb[c])), thread tid = c ----
    float acc = 0.0f;
    {
        const float4* pwr = reinterpret_cast<const float4*>(pw + tid * C);
        #pragma unroll 16
        for (int k4 = 0; k4 < C / 4; ++k4) {
            const float4 wv = pwr[k4];
            const float* tfk = &tf_sh[k4 * 4];
            acc += wv.x * tfk[0] + wv.y * tfk[1] + wv.z * tfk[2] + wv.w * tfk[3];
        }
    }
    float t;
    {
        const float scale = g[tid] * rsqrtf(var[tid] + 1e-5f);
        t = (acc + pb[tid] - mu[tid]) * scale + be[tid];
        t = fmaxf(t, 0.0f);
        t_sh[tid] = t;
    }

    // ---- per-batch sum / max over C (wave shuffle + LDS combine) ----
    {
        float s = t, m = t;
        #pragma unroll
        for (int off = 32; off > 0; off >>= 1) {
            s += __shfl_down(s, off);
            m  = fmaxf(m, __shfl_down(m, off));
        }
        const int wv_ = tid >> 6;
        if ((tid & 63) == 0) { red[wv_] = s; red[4 + wv_] = m; }
        __syncthreads();
        if (tid == 0) {
            s_stats[0] = (red[0] + red[1] + red[2] + red[3]) * (1.0f / C);
            s_stats[1] = fmaxf(fmaxf(red[4], red[5]), fmaxf(red[6], red[7]));
        }
        __syncthreads();
    }

    // ---- 49-entry sw table: threads 0..48, taps from LDS ----
    if (tid < 49) {
        const int yc = tid / 7, xc = tid % 7;
        const int ky0 = yc < 3 ? 3 - yc : 0;
        const int ky1 = yc > 3 ? 9 - yc : 6;   // yc=4->5, 5->4, 6->3
        const int kx0 = xc < 3 ? 3 - xc : 0;
        const int kx1 = xc > 3 ? 9 - xc : 6;
        float S0 = 0.0f, S1 = 0.0f;
        for (int ky = ky0; ky <= ky1; ++ky)
            for (int kx = kx0; kx <= kx1; ++kx) {
                S0 += saw_sh[ky * 7 + kx];
                S1 += saw_sh[49 + ky * 7 + kx];
            }
        tbl[b * 49 + tid] = sigmoidf_(s_stats[0] * S0 + s_stats[1] * S1 + sab[0]);
    }

    // ---- h[r] = relu(ca_w1[r,:]·t + b1[r]), threads 0..63 ----
    if (tid < CR) {
        float a = b1[tid];
        const float4* w1r = reinterpret_cast<const float4*>(w1 + tid * C);
        #pragma unroll 16
        for (int k4 = 0; k4 < C / 4; ++k4) {
            const float4 wv = w1r[k4];
            const float* tk = &t_sh[k4 * 4];
            a += wv.x * tk[0] + wv.y * tk[1] + wv.z * tk[2] + wv.w * tk[3];
        }
        h_sh[tid] = fmaxf(a, 0.0f);
    }
    __syncthreads();

    // ---- cw[c] = sigmoid(ca_w2[c,:]·h + b2[c]) ----
    {
        float a = b2[tid];
        const float4* w2r = reinterpret_cast<const float4*>(w2 + tid * CR);
        #pragma unroll
        for (int r4 = 0; r4 < CR / 4; ++r4) {
            const float4 wv = w2r[r4];
            const float* hk = &h_sh[r4 * 4];
            a += wv.x * hk[0] + wv.y * hk[1] + wv.z * hk[2] + wv.w * hk[3];
        }
        cw[b * C + tid] = sigmoidf_(a);
    }
}

// ---------------------------------------------------------------------------
// Kernel C: out[b,c,y,x] = x * cw[b,c] * sw_class_value.
// Grid (1024, B): b constant per block; per-thread spatial class constant
// across all iterations. Plain (cached) loads/stores — A/B vs R6's
// nontemporal hints, which are the suspected BW cap.
// ---------------------------------------------------------------------------
__global__ __launch_bounds__(256)
void fuse_kernel(const floatx4* __restrict__ x4,
                 const float*   __restrict__ cw,    // (B,C)
                 const float*   __restrict__ tbl,   // (B,49)
                 floatx4* __restrict__ out4)
{
    __shared__ float cw_sh[C];      // this batch's channel weights
    __shared__ float tbl_sh[49];    // this batch's sw class table

    const int b   = blockIdx.y;
    const int tid = threadIdx.x;
    cw_sh[tid] = cw[b * C + tid];
    if (tid < 49) tbl_sh[tid] = tbl[b * 49 + tid];
    __syncthreads();

    const int local0 = blockIdx.x * 256 + tid;     // [0, 262144)
    // spatial classification — constant across iterations
    const int s4 = local0 & 4095;                  // float4 index within plane
    const int y  = s4 >> 5;                        // 32 float4 per row
    const int xg = s4 & 31;
    const int yc = y < 3 ? y : (y > 124 ? y - 121 : 3);
    const float* tb = &tbl_sh[yc * 7];
    float s0, s1, s2, s3;
    if (xg == 0)       { s0 = tb[0]; s1 = tb[1]; s2 = tb[2]; s3 = tb[3]; }
    else if (xg == 31) { s0 = tb[3]; s1 = tb[4]; s2 = tb[5]; s3 = tb[6]; }
    else               { s0 = s1 = s2 = s3 = tb[3]; }

    const long base = (long)b * PER_BATCH4;
    const int  c0   = local0 >> 12;                // channel of iter 0

    #pragma unroll
    for (int i = 0; i < FUSE_ITERS; ++i) {
        const long j   = base + local0 + (long)i * FUSE_STRIDE;
        const float cwv = cw_sh[c0 + i * (FUSE_STRIDE >> 12)];
        const floatx4 xs = x4[j];
        floatx4 o;
        o.x = xs.x * cwv * s0;
        o.y = xs.y * cwv * s1;
        o.z = xs.z * cwv * s2;
        o.w = xs.w * cwv * s3;
        out4[j] = o;
    }
}

// ---------------------------------------------------------------------------
extern "C" void kernel_launch(void* const* d_in, const int* in_sizes, int n_in,
                              void* d_out, int out_size, void* d_ws, size_t ws_size,
                              hipStream_t stream) {
    const float* x    = (const float*)d_in[0];
    const float* tf   = (const float*)d_in[1];
    const float* pw   = (const float*)d_in[2];
    const float* pb   = (const float*)d_in[3];
    const float* g    = (const float*)d_in[4];
    const float* be   = (const float*)d_in[5];
    const float* mu   = (const float*)d_in[6];
    const float* var  = (const float*)d_in[7];
    const float* w1   = (const float*)d_in[8];
    const float* b1   = (const float*)d_in[9];
    const float* w2   = (const float*)d_in[10];
    const float* b2   = (const float*)d_in[11];
    const float* saw  = (const float*)d_in[12];
    const float* sab  = (const float*)d_in[13];
    float* out = (float*)d_out;

    // workspace layout (floats): cw[2048] | tbl[392]
    float* wsf = (float*)d_ws;
    float* cw  = wsf;
    float* tbl = wsf + 2048;

    setup_kernel<<<B, 256, 0, stream>>>(tf, pw, pb, g, be, mu, var,
                                        w1, b1, w2, b2, saw, sab, cw, tbl);
    fuse_kernel<<<dim3(FUSE_BLOCKS_X, B), 256, 0, stream>>>(
        (const floatx4*)x, cw, tbl, (floatx4*)out);
}